// Round 1
// baseline (839.226 us; speedup 1.0000x reference)
//
#include <hip/hip_runtime.h>

#define Nn 50000
#define Dd 128
#define Cc 300

__device__ __forceinline__ float lrelu(float x) { return x > 0.f ? x : 0.1f * x; }

// ---------------- CSR build ----------------

__global__ void k_degree(const int* __restrict__ edst, int* __restrict__ deg, int ET) {
    int i = blockIdx.x * 256 + threadIdx.x;
    if (i < ET) atomicAdd(&deg[edst[i]], 1);
}

__global__ __launch_bounds__(1024) void k_scan(const int* __restrict__ deg,
                                               int* __restrict__ offs,
                                               int* __restrict__ cursor, int n) {
    __shared__ int wsum[16];
    __shared__ int woff[16];
    __shared__ int s_carry;
    int tid = threadIdx.x, lane = tid & 63, wid = tid >> 6;
    if (tid == 0) s_carry = 0;
    __syncthreads();
    for (int base = 0; base < n; base += 1024) {
        int i = base + tid;
        int v = (i < n) ? deg[i] : 0;
        int incl = v;
        #pragma unroll
        for (int off = 1; off < 64; off <<= 1) {
            int t = __shfl_up(incl, off, 64);
            if (lane >= off) incl += t;
        }
        if (lane == 63) wsum[wid] = incl;
        __syncthreads();
        if (tid == 0) {
            int run = 0;
            #pragma unroll
            for (int w = 0; w < 16; ++w) { woff[w] = run; run += wsum[w]; }
            wsum[0] = run;  // chunk total
        }
        __syncthreads();
        int excl = s_carry + woff[wid] + incl - v;
        if (i < n) { offs[i] = excl; cursor[i] = excl; }
        int ctot = wsum[0];
        __syncthreads();
        if (tid == 0) s_carry += ctot;
        __syncthreads();
    }
    if (tid == 0) offs[n] = s_carry;
}

__global__ void k_scatter(const int* __restrict__ esrc, const int* __restrict__ edst,
                          int* __restrict__ cursor, int* __restrict__ bucket, int ET) {
    int i = blockIdx.x * 256 + threadIdx.x;
    if (i < ET) {
        int d = edst[i];
        int pos = atomicAdd(&cursor[d], 1);
        bucket[pos] = esrc[i];
    }
}

// ---------------- neighbor aggregation (wave per node) ----------------

__global__ __launch_bounds__(256) void k_agg(const float* __restrict__ h,
                                             const int* __restrict__ offs,
                                             const int* __restrict__ bucket,
                                             float* __restrict__ agg) {
    int node = blockIdx.x * 4 + (threadIdx.x >> 6);
    if (node >= Nn) return;
    int lane = threadIdx.x & 63;
    const float2* h2 = (const float2*)h;
    int s = offs[node], e = offs[node + 1];
    float ax = 0.f, ay = 0.f;
    int p = s;
    for (; p + 2 <= e; p += 2) {
        int s0 = bucket[p], s1 = bucket[p + 1];
        float2 v0 = h2[(size_t)s0 * 64 + lane];
        float2 v1 = h2[(size_t)s1 * 64 + lane];
        ax += v0.x + v1.x;
        ay += v0.y + v1.y;
    }
    if (p < e) {
        int s0 = bucket[p];
        float2 v0 = h2[(size_t)s0 * 64 + lane];
        ax += v0.x;
        ay += v0.y;
    }
    float2 self = h2[(size_t)node * 64 + lane];
    float inv = 1.f / fmaxf((float)(e - s) - 1.f, 1.f);
    float2 r;
    r.x = (ax - self.x) * inv;
    r.y = (ay - self.y) * inv;
    ((float2*)agg)[(size_t)node * 64 + lane] = r;
}

// ---------------- h0 = emb[i+1] + lrelu(content @ projW^T + b) ----------------
// GEMM [50000 x 300] @ [300 x 128], BM=64 BN=128 BK=60, 256 thr, 4x8/thread

__global__ __launch_bounds__(256) void k_h0(const float* __restrict__ content,
                                            const float* __restrict__ projW,
                                            const float* __restrict__ projB,
                                            const float* __restrict__ emb,
                                            float* __restrict__ h) {
    __shared__ float sA[64][61];    // row-major A tile; 4*61%32=20 -> 2-way on a-reads
    __shared__ float sWT[60][132];  // transposed W tile; 132*4%16==0 -> float4 reads ok
    int bm = blockIdx.x * 64;
    int tid = threadIdx.x;
    int tx = tid & 15, ty = tid >> 4;
    float acc[4][8];
    #pragma unroll
    for (int r = 0; r < 4; ++r)
        #pragma unroll
        for (int j = 0; j < 8; ++j) acc[r][j] = 0.f;

    for (int k0 = 0; k0 < Cc; k0 += 60) {
        for (int idx = tid; idx < 64 * 15; idx += 256) {
            int r = idx / 15, c4 = idx % 15;
            int gi = bm + r;
            float4 v = make_float4(0.f, 0.f, 0.f, 0.f);
            if (gi < Nn) v = *(const float4*)(content + (size_t)gi * Cc + k0 + c4 * 4);
            sA[r][c4 * 4 + 0] = v.x;
            sA[r][c4 * 4 + 1] = v.y;
            sA[r][c4 * 4 + 2] = v.z;
            sA[r][c4 * 4 + 3] = v.w;
        }
        for (int idx = tid; idx < 128 * 15; idx += 256) {
            int d = idx / 15, c4 = idx % 15;
            float4 v = *(const float4*)(projW + (size_t)d * Cc + k0 + c4 * 4);
            sWT[c4 * 4 + 0][d] = v.x;
            sWT[c4 * 4 + 1][d] = v.y;
            sWT[c4 * 4 + 2][d] = v.z;
            sWT[c4 * 4 + 3][d] = v.w;
        }
        __syncthreads();
        #pragma unroll 4
        for (int kk = 0; kk < 60; ++kk) {
            float a0 = sA[ty * 4 + 0][kk];
            float a1 = sA[ty * 4 + 1][kk];
            float a2 = sA[ty * 4 + 2][kk];
            float a3 = sA[ty * 4 + 3][kk];
            const float4* bp = (const float4*)&sWT[kk][tx * 8];
            float4 b0 = bp[0], b1 = bp[1];
            float bb[8] = {b0.x, b0.y, b0.z, b0.w, b1.x, b1.y, b1.z, b1.w};
            #pragma unroll
            for (int j = 0; j < 8; ++j) {
                acc[0][j] = fmaf(a0, bb[j], acc[0][j]);
                acc[1][j] = fmaf(a1, bb[j], acc[1][j]);
                acc[2][j] = fmaf(a2, bb[j], acc[2][j]);
                acc[3][j] = fmaf(a3, bb[j], acc[3][j]);
            }
        }
        __syncthreads();
    }

    float4 pb0 = *(const float4*)(projB + tx * 8);
    float4 pb1 = *(const float4*)(projB + tx * 8 + 4);
    float pb[8] = {pb0.x, pb0.y, pb0.z, pb0.w, pb1.x, pb1.y, pb1.z, pb1.w};
    #pragma unroll
    for (int r = 0; r < 4; ++r) {
        int gi = bm + ty * 4 + r;
        if (gi >= Nn) continue;
        float4 e0 = *(const float4*)(emb + (size_t)(gi + 1) * Dd + tx * 8);
        float4 e1 = *(const float4*)(emb + (size_t)(gi + 1) * Dd + tx * 8 + 4);
        float o[8];
        #pragma unroll
        for (int j = 0; j < 8; ++j) o[j] = lrelu(acc[r][j] + pb[j]);
        o[0] += e0.x; o[1] += e0.y; o[2] += e0.z; o[3] += e0.w;
        o[4] += e1.x; o[5] += e1.y; o[6] += e1.z; o[7] += e1.w;
        *(float4*)(h + (size_t)gi * Dd + tx * 8) = make_float4(o[0], o[1], o[2], o[3]);
        *(float4*)(h + (size_t)gi * Dd + tx * 8 + 4) = make_float4(o[4], o[5], o[6], o[7]);
    }
}

// ---------------- SAGE layer: out = rownorm(act(concat(h,agg) @ W^T + b)) ----------------
// K=256 in 4 chunks of 64 (2 from h, 2 from agg). Note: h/out may alias (no restrict).

template <bool ACT>
__global__ __launch_bounds__(256) void k_layer(const float* h, const float* __restrict__ agg,
                                               const float* __restrict__ W,
                                               const float* __restrict__ bias, float* out) {
    __shared__ float sA[64][65];    // 4*65%32=4 -> 2-way on a-reads
    __shared__ float sBT[64][132];  // transposed W chunk
    int bm = blockIdx.x * 64;
    int tid = threadIdx.x, tx = tid & 15, ty = tid >> 4;
    float acc[4][8];
    #pragma unroll
    for (int r = 0; r < 4; ++r)
        #pragma unroll
        for (int j = 0; j < 8; ++j) acc[r][j] = 0.f;

    for (int kc = 0; kc < 4; ++kc) {
        const float* Asrc = (kc < 2) ? h : agg;
        int k0 = (kc & 1) * 64;
        int wk0 = kc * 64;
        for (int idx = tid; idx < 64 * 16; idx += 256) {
            int r = idx / 16, c4 = idx % 16;
            int gi = bm + r;
            float4 v = make_float4(0.f, 0.f, 0.f, 0.f);
            if (gi < Nn) v = *(const float4*)(Asrc + (size_t)gi * Dd + k0 + c4 * 4);
            sA[r][c4 * 4 + 0] = v.x;
            sA[r][c4 * 4 + 1] = v.y;
            sA[r][c4 * 4 + 2] = v.z;
            sA[r][c4 * 4 + 3] = v.w;
        }
        for (int idx = tid; idx < 128 * 16; idx += 256) {
            int d = idx / 16, c4 = idx % 16;
            float4 v = *(const float4*)(W + (size_t)d * 256 + wk0 + c4 * 4);
            sBT[c4 * 4 + 0][d] = v.x;
            sBT[c4 * 4 + 1][d] = v.y;
            sBT[c4 * 4 + 2][d] = v.z;
            sBT[c4 * 4 + 3][d] = v.w;
        }
        __syncthreads();
        #pragma unroll 4
        for (int kk = 0; kk < 64; ++kk) {
            float a0 = sA[ty * 4 + 0][kk];
            float a1 = sA[ty * 4 + 1][kk];
            float a2 = sA[ty * 4 + 2][kk];
            float a3 = sA[ty * 4 + 3][kk];
            const float4* bp = (const float4*)&sBT[kk][tx * 8];
            float4 b0 = bp[0], b1 = bp[1];
            float bb[8] = {b0.x, b0.y, b0.z, b0.w, b1.x, b1.y, b1.z, b1.w};
            #pragma unroll
            for (int j = 0; j < 8; ++j) {
                acc[0][j] = fmaf(a0, bb[j], acc[0][j]);
                acc[1][j] = fmaf(a1, bb[j], acc[1][j]);
                acc[2][j] = fmaf(a2, bb[j], acc[2][j]);
                acc[3][j] = fmaf(a3, bb[j], acc[3][j]);
            }
        }
        __syncthreads();
    }

    float4 bb0 = *(const float4*)(bias + tx * 8);
    float4 bb1 = *(const float4*)(bias + tx * 8 + 4);
    float bv[8] = {bb0.x, bb0.y, bb0.z, bb0.w, bb1.x, bb1.y, bb1.z, bb1.w};
    #pragma unroll
    for (int r = 0; r < 4; ++r) {
        float s = 0.f;
        #pragma unroll
        for (int j = 0; j < 8; ++j) {
            float v = acc[r][j] + bv[j];
            if (ACT) v = lrelu(v);
            acc[r][j] = v;
            s += v * v;
        }
        #pragma unroll
        for (int off = 8; off >= 1; off >>= 1) s += __shfl_xor(s, off, 16);
        float inv = 1.f / fmaxf(sqrtf(s), 1e-6f);
        int gi = bm + ty * 4 + r;
        if (gi < Nn) {
            *(float4*)(out + (size_t)gi * Dd + tx * 8) =
                make_float4(acc[r][0] * inv, acc[r][1] * inv, acc[r][2] * inv, acc[r][3] * inv);
            *(float4*)(out + (size_t)gi * Dd + tx * 8 + 4) =
                make_float4(acc[r][4] * inv, acc[r][5] * inv, acc[r][6] * inv, acc[r][7] * inv);
        }
    }
}

// ---------------- launch ----------------

extern "C" void kernel_launch(void* const* d_in, const int* in_sizes, int n_in,
                              void* d_out, int out_size, void* d_ws, size_t ws_size,
                              hipStream_t stream) {
    const float* node_emb = (const float*)d_in[0];
    const float* content  = (const float*)d_in[1];
    const float* projW    = (const float*)d_in[2];
    const float* projB    = (const float*)d_in[3];
    const float* W1 = (const float*)d_in[4];
    const float* b1 = (const float*)d_in[5];
    const float* W2 = (const float*)d_in[6];
    const float* b2 = (const float*)d_in[7];
    const int* esrc = (const int*)d_in[8];
    const int* edst = (const int*)d_in[9];
    const int ET = in_sizes[8];
    float* out = (float*)d_out;

    // workspace layout (~58.4 MB)
    float* h0  = (float*)d_ws;                      // N*128 f32
    float* agg = h0 + (size_t)Nn * Dd;              // N*128 f32
    int* deg    = (int*)(agg + (size_t)Nn * Dd);    // N
    int* offs   = deg + Nn;                         // N+1
    int* cursor = offs + Nn + 1;                    // N
    int* bucket = cursor + Nn;                      // ET

    hipMemsetAsync(deg, 0, Nn * sizeof(int), stream);
    k_degree<<<(ET + 255) / 256, 256, 0, stream>>>(edst, deg, ET);
    k_scan<<<1, 1024, 0, stream>>>(deg, offs, cursor, Nn);
    k_scatter<<<(ET + 255) / 256, 256, 0, stream>>>(esrc, edst, cursor, bucket, ET);

    k_h0<<<(Nn + 63) / 64, 256, 0, stream>>>(content, projW, projB, node_emb, h0);

    k_agg<<<(Nn + 3) / 4, 256, 0, stream>>>(h0, offs, bucket, agg);
    k_layer<true><<<(Nn + 63) / 64, 256, 0, stream>>>(h0, agg, W1, b1, out);  // h1 lives in d_out

    k_agg<<<(Nn + 3) / 4, 256, 0, stream>>>(out, offs, bucket, agg);
    k_layer<false><<<(Nn + 63) / 64, 256, 0, stream>>>(out, agg, W2, b2, out);
}

// Round 2
// 642.288 us; speedup vs baseline: 1.3066x; 1.3066x over previous
//
#include <hip/hip_runtime.h>

#define Nn 50000
#define Dd 128
#define Cc 300

#define BIN_SHIFT 7
#define BIN_W (1 << BIN_SHIFT)                    // 128 nodes per bin
#define NBINS ((Nn + BIN_W - 1) >> BIN_SHIFT)     // 391
#define CAP 8192                                  // max edges per bin (mean ~4220)
#define CHUNK 8192

__device__ __forceinline__ float lrelu(float x) { return x > 0.f ? x : 0.1f * x; }

// ---------------- CSR build via two-level counting sort ----------------

__global__ __launch_bounds__(256) void k_bincount(const int* __restrict__ edst,
                                                  int* __restrict__ binCount, int ET) {
    __shared__ int h[NBINS];
    for (int i = threadIdx.x; i < NBINS; i += 256) h[i] = 0;
    __syncthreads();
    for (int i = blockIdx.x * 256 + threadIdx.x; i < ET; i += gridDim.x * 256)
        atomicAdd(&h[edst[i] >> BIN_SHIFT], 1);
    __syncthreads();
    for (int i = threadIdx.x; i < NBINS; i += 256)
        if (h[i]) atomicAdd(&binCount[i], h[i]);
}

__global__ __launch_bounds__(512) void k_binscan(const int* __restrict__ binCount,
                                                 int* __restrict__ binBase,
                                                 int* __restrict__ binCursor,
                                                 int* __restrict__ offs, int ET) {
    __shared__ int wsum[8];
    int tid = threadIdx.x, lane = tid & 63, wid = tid >> 6;
    int v = (tid < NBINS) ? binCount[tid] : 0;
    int incl = v;
    #pragma unroll
    for (int off = 1; off < 64; off <<= 1) {
        int t = __shfl_up(incl, off, 64);
        if (lane >= off) incl += t;
    }
    if (lane == 63) wsum[wid] = incl;
    __syncthreads();
    if (tid == 0) {
        int run = 0;
        #pragma unroll
        for (int w = 0; w < 8; ++w) { int t = wsum[w]; wsum[w] = run; run += t; }
    }
    __syncthreads();
    int excl = wsum[wid] + incl - v;
    if (tid < NBINS) { binBase[tid] = excl; binCursor[tid] = excl; }
    if (tid == NBINS) binBase[NBINS] = excl;  // total
    if (tid == 0) offs[Nn] = ET;
}

__global__ __launch_bounds__(256) void k_binscatter(const int* __restrict__ esrc,
                                                    const int* __restrict__ edst,
                                                    int* __restrict__ binCursor,
                                                    uint2* __restrict__ pairs, int ET) {
    __shared__ int hist[NBINS];
    __shared__ int base[NBINS];
    __shared__ int ssrc[CHUNK];
    __shared__ int sdst[CHUNK];
    int c0 = blockIdx.x * CHUNK;
    int n = min(CHUNK, ET - c0);
    for (int i = threadIdx.x; i < NBINS; i += 256) hist[i] = 0;
    __syncthreads();
    for (int i = threadIdx.x; i < n; i += 256) {
        int s = esrc[c0 + i], d = edst[c0 + i];
        ssrc[i] = s; sdst[i] = d;
        atomicAdd(&hist[d >> BIN_SHIFT], 1);
    }
    __syncthreads();
    for (int i = threadIdx.x; i < NBINS; i += 256) {
        int c = hist[i];
        base[i] = c ? atomicAdd(&binCursor[i], c) : 0;
        hist[i] = 0;  // reuse as local cursor
    }
    __syncthreads();
    for (int i = threadIdx.x; i < n; i += 256) {
        int d = sdst[i];
        int b = d >> BIN_SHIFT;
        int p = base[b] + atomicAdd(&hist[b], 1);
        pairs[p] = make_uint2((unsigned)ssrc[i], (unsigned)d);
    }
}

__global__ __launch_bounds__(256) void k_binsort(const uint2* __restrict__ pairs,
                                                 const int* __restrict__ binBase,
                                                 int* __restrict__ offs,
                                                 int* __restrict__ bucket) {
    __shared__ int cnt[BIN_W];
    __shared__ int cur[BIN_W];
    __shared__ int srcbuf[CAP];
    __shared__ int w0sum;
    int bin = blockIdx.x;
    int e0 = binBase[bin], e1 = binBase[bin + 1];
    int n = e1 - e0;
    int tid = threadIdx.x;
    if (tid < BIN_W) cnt[tid] = 0;
    __syncthreads();
    const uint2* p2 = pairs + e0;
    for (int i = tid; i < n; i += 256)
        atomicAdd(&cnt[p2[i].y & (BIN_W - 1)], 1);
    __syncthreads();
    int v = 0, incl = 0;
    if (tid < BIN_W) {
        v = cnt[tid];
        incl = v;
        #pragma unroll
        for (int off = 1; off < 64; off <<= 1) {
            int t = __shfl_up(incl, off, 64);
            if ((tid & 63) >= off) incl += t;
        }
    }
    if (tid == 63) w0sum = incl;
    __syncthreads();
    if (tid < BIN_W) {
        int excl = incl - v + (tid >= 64 ? w0sum : 0);
        cur[tid] = excl;
        int node = (bin << BIN_SHIFT) + tid;
        if (node < Nn) offs[node] = e0 + excl;
    }
    __syncthreads();
    for (int i = tid; i < n; i += 256) {
        uint2 pr = p2[i];
        int p = atomicAdd(&cur[pr.y & (BIN_W - 1)], 1);
        if (p < CAP) srcbuf[p] = (int)pr.x;
    }
    __syncthreads();
    for (int i = tid; i < n; i += 256) bucket[e0 + i] = srcbuf[i];
}

// ---------------- neighbor aggregation (wave per node) ----------------

__global__ __launch_bounds__(256) void k_agg(const float* __restrict__ h,
                                             const int* __restrict__ offs,
                                             const int* __restrict__ bucket,
                                             float* __restrict__ agg) {
    int node = blockIdx.x * 4 + (threadIdx.x >> 6);
    if (node >= Nn) return;
    int lane = threadIdx.x & 63;
    const float2* h2 = (const float2*)h;
    int s = offs[node], e = offs[node + 1];
    float ax = 0.f, ay = 0.f;
    int p = s;
    for (; p + 4 <= e; p += 4) {
        int s0 = bucket[p], s1 = bucket[p + 1], s2 = bucket[p + 2], s3 = bucket[p + 3];
        float2 v0 = h2[(size_t)s0 * 64 + lane];
        float2 v1 = h2[(size_t)s1 * 64 + lane];
        float2 v2 = h2[(size_t)s2 * 64 + lane];
        float2 v3 = h2[(size_t)s3 * 64 + lane];
        ax += (v0.x + v1.x) + (v2.x + v3.x);
        ay += (v0.y + v1.y) + (v2.y + v3.y);
    }
    for (; p < e; ++p) {
        int s0 = bucket[p];
        float2 v0 = h2[(size_t)s0 * 64 + lane];
        ax += v0.x;
        ay += v0.y;
    }
    float2 self = h2[(size_t)node * 64 + lane];
    float inv = 1.f / fmaxf((float)(e - s) - 1.f, 1.f);
    float2 r;
    r.x = (ax - self.x) * inv;
    r.y = (ay - self.y) * inv;
    ((float2*)agg)[(size_t)node * 64 + lane] = r;
}

// ---------------- h0 = emb[i+1] + lrelu(content @ projW^T + b) ----------------

__global__ __launch_bounds__(256) void k_h0(const float* __restrict__ content,
                                            const float* __restrict__ projW,
                                            const float* __restrict__ projB,
                                            const float* __restrict__ emb,
                                            float* __restrict__ h) {
    __shared__ float sA[64][61];
    __shared__ float sWT[60][132];
    int bm = blockIdx.x * 64;
    int tid = threadIdx.x;
    int tx = tid & 15, ty = tid >> 4;
    float acc[4][8];
    #pragma unroll
    for (int r = 0; r < 4; ++r)
        #pragma unroll
        for (int j = 0; j < 8; ++j) acc[r][j] = 0.f;

    for (int k0 = 0; k0 < Cc; k0 += 60) {
        for (int idx = tid; idx < 64 * 15; idx += 256) {
            int r = idx / 15, c4 = idx % 15;
            int gi = bm + r;
            float4 v = make_float4(0.f, 0.f, 0.f, 0.f);
            if (gi < Nn) v = *(const float4*)(content + (size_t)gi * Cc + k0 + c4 * 4);
            sA[r][c4 * 4 + 0] = v.x;
            sA[r][c4 * 4 + 1] = v.y;
            sA[r][c4 * 4 + 2] = v.z;
            sA[r][c4 * 4 + 3] = v.w;
        }
        for (int idx = tid; idx < 128 * 15; idx += 256) {
            int d = idx / 15, c4 = idx % 15;
            float4 v = *(const float4*)(projW + (size_t)d * Cc + k0 + c4 * 4);
            sWT[c4 * 4 + 0][d] = v.x;
            sWT[c4 * 4 + 1][d] = v.y;
            sWT[c4 * 4 + 2][d] = v.z;
            sWT[c4 * 4 + 3][d] = v.w;
        }
        __syncthreads();
        #pragma unroll 4
        for (int kk = 0; kk < 60; ++kk) {
            float a0 = sA[ty * 4 + 0][kk];
            float a1 = sA[ty * 4 + 1][kk];
            float a2 = sA[ty * 4 + 2][kk];
            float a3 = sA[ty * 4 + 3][kk];
            const float4* bp = (const float4*)&sWT[kk][tx * 8];
            float4 b0 = bp[0], b1 = bp[1];
            float bb[8] = {b0.x, b0.y, b0.z, b0.w, b1.x, b1.y, b1.z, b1.w};
            #pragma unroll
            for (int j = 0; j < 8; ++j) {
                acc[0][j] = fmaf(a0, bb[j], acc[0][j]);
                acc[1][j] = fmaf(a1, bb[j], acc[1][j]);
                acc[2][j] = fmaf(a2, bb[j], acc[2][j]);
                acc[3][j] = fmaf(a3, bb[j], acc[3][j]);
            }
        }
        __syncthreads();
    }

    float4 pb0 = *(const float4*)(projB + tx * 8);
    float4 pb1 = *(const float4*)(projB + tx * 8 + 4);
    float pb[8] = {pb0.x, pb0.y, pb0.z, pb0.w, pb1.x, pb1.y, pb1.z, pb1.w};
    #pragma unroll
    for (int r = 0; r < 4; ++r) {
        int gi = bm + ty * 4 + r;
        if (gi >= Nn) continue;
        float4 e0 = *(const float4*)(emb + (size_t)(gi + 1) * Dd + tx * 8);
        float4 e1 = *(const float4*)(emb + (size_t)(gi + 1) * Dd + tx * 8 + 4);
        float o[8];
        #pragma unroll
        for (int j = 0; j < 8; ++j) o[j] = lrelu(acc[r][j] + pb[j]);
        o[0] += e0.x; o[1] += e0.y; o[2] += e0.z; o[3] += e0.w;
        o[4] += e1.x; o[5] += e1.y; o[6] += e1.z; o[7] += e1.w;
        *(float4*)(h + (size_t)gi * Dd + tx * 8) = make_float4(o[0], o[1], o[2], o[3]);
        *(float4*)(h + (size_t)gi * Dd + tx * 8 + 4) = make_float4(o[4], o[5], o[6], o[7]);
    }
}

// ---------------- SAGE layer ----------------

template <bool ACT>
__global__ __launch_bounds__(256) void k_layer(const float* h, const float* __restrict__ agg,
                                               const float* __restrict__ W,
                                               const float* __restrict__ bias, float* out) {
    __shared__ float sA[64][65];
    __shared__ float sBT[64][132];
    int bm = blockIdx.x * 64;
    int tid = threadIdx.x, tx = tid & 15, ty = tid >> 4;
    float acc[4][8];
    #pragma unroll
    for (int r = 0; r < 4; ++r)
        #pragma unroll
        for (int j = 0; j < 8; ++j) acc[r][j] = 0.f;

    for (int kc = 0; kc < 4; ++kc) {
        const float* Asrc = (kc < 2) ? h : agg;
        int k0 = (kc & 1) * 64;
        int wk0 = kc * 64;
        for (int idx = tid; idx < 64 * 16; idx += 256) {
            int r = idx / 16, c4 = idx % 16;
            int gi = bm + r;
            float4 v = make_float4(0.f, 0.f, 0.f, 0.f);
            if (gi < Nn) v = *(const float4*)(Asrc + (size_t)gi * Dd + k0 + c4 * 4);
            sA[r][c4 * 4 + 0] = v.x;
            sA[r][c4 * 4 + 1] = v.y;
            sA[r][c4 * 4 + 2] = v.z;
            sA[r][c4 * 4 + 3] = v.w;
        }
        for (int idx = tid; idx < 128 * 16; idx += 256) {
            int d = idx / 16, c4 = idx % 16;
            float4 v = *(const float4*)(W + (size_t)d * 256 + wk0 + c4 * 4);
            sBT[c4 * 4 + 0][d] = v.x;
            sBT[c4 * 4 + 1][d] = v.y;
            sBT[c4 * 4 + 2][d] = v.z;
            sBT[c4 * 4 + 3][d] = v.w;
        }
        __syncthreads();
        #pragma unroll 4
        for (int kk = 0; kk < 64; ++kk) {
            float a0 = sA[ty * 4 + 0][kk];
            float a1 = sA[ty * 4 + 1][kk];
            float a2 = sA[ty * 4 + 2][kk];
            float a3 = sA[ty * 4 + 3][kk];
            const float4* bp = (const float4*)&sBT[kk][tx * 8];
            float4 b0 = bp[0], b1 = bp[1];
            float bb[8] = {b0.x, b0.y, b0.z, b0.w, b1.x, b1.y, b1.z, b1.w};
            #pragma unroll
            for (int j = 0; j < 8; ++j) {
                acc[0][j] = fmaf(a0, bb[j], acc[0][j]);
                acc[1][j] = fmaf(a1, bb[j], acc[1][j]);
                acc[2][j] = fmaf(a2, bb[j], acc[2][j]);
                acc[3][j] = fmaf(a3, bb[j], acc[3][j]);
            }
        }
        __syncthreads();
    }

    float4 bb0 = *(const float4*)(bias + tx * 8);
    float4 bb1 = *(const float4*)(bias + tx * 8 + 4);
    float bv[8] = {bb0.x, bb0.y, bb0.z, bb0.w, bb1.x, bb1.y, bb1.z, bb1.w};
    #pragma unroll
    for (int r = 0; r < 4; ++r) {
        float s = 0.f;
        #pragma unroll
        for (int j = 0; j < 8; ++j) {
            float v = acc[r][j] + bv[j];
            if (ACT) v = lrelu(v);
            acc[r][j] = v;
            s += v * v;
        }
        #pragma unroll
        for (int off = 8; off >= 1; off >>= 1) s += __shfl_xor(s, off, 16);
        float inv = 1.f / fmaxf(sqrtf(s), 1e-6f);
        int gi = bm + ty * 4 + r;
        if (gi < Nn) {
            *(float4*)(out + (size_t)gi * Dd + tx * 8) =
                make_float4(acc[r][0] * inv, acc[r][1] * inv, acc[r][2] * inv, acc[r][3] * inv);
            *(float4*)(out + (size_t)gi * Dd + tx * 8 + 4) =
                make_float4(acc[r][4] * inv, acc[r][5] * inv, acc[r][6] * inv, acc[r][7] * inv);
        }
    }
}

// ---------------- launch ----------------

extern "C" void kernel_launch(void* const* d_in, const int* in_sizes, int n_in,
                              void* d_out, int out_size, void* d_ws, size_t ws_size,
                              hipStream_t stream) {
    const float* node_emb = (const float*)d_in[0];
    const float* content  = (const float*)d_in[1];
    const float* projW    = (const float*)d_in[2];
    const float* projB    = (const float*)d_in[3];
    const float* W1 = (const float*)d_in[4];
    const float* b1 = (const float*)d_in[5];
    const float* W2 = (const float*)d_in[6];
    const float* b2 = (const float*)d_in[7];
    const int* esrc = (const int*)d_in[8];
    const int* edst = (const int*)d_in[9];
    const int ET = in_sizes[8];
    float* out = (float*)d_out;

    // workspace layout (~71 MB)
    float* h0  = (float*)d_ws;                       // N*128 f32
    float* agg = h0 + (size_t)Nn * Dd;               // N*128 f32
    int* offs      = (int*)(agg + (size_t)Nn * Dd);  // N+1
    int* binCount  = offs + Nn + 1;                  // NBINS
    int* binBase   = binCount + NBINS;               // NBINS+1
    int* binCursor = binBase + NBINS + 1;            // NBINS
    int* bucket    = binCursor + NBINS;              // ET
    uintptr_t pa = (uintptr_t)(bucket + ET);
    pa = (pa + 15) & ~(uintptr_t)15;
    uint2* pairs = (uint2*)pa;                       // ET * 8B

    hipMemsetAsync(binCount, 0, NBINS * sizeof(int), stream);
    k_bincount<<<256, 256, 0, stream>>>(edst, binCount, ET);
    k_binscan<<<1, 512, 0, stream>>>(binCount, binBase, binCursor, offs, ET);
    k_binscatter<<<(ET + CHUNK - 1) / CHUNK, 256, 0, stream>>>(esrc, edst, binCursor, pairs, ET);
    k_binsort<<<NBINS, 256, 0, stream>>>(pairs, binBase, offs, bucket);

    k_h0<<<(Nn + 63) / 64, 256, 0, stream>>>(content, projW, projB, node_emb, h0);

    k_agg<<<(Nn + 3) / 4, 256, 0, stream>>>(h0, offs, bucket, agg);
    k_layer<true><<<(Nn + 63) / 64, 256, 0, stream>>>(h0, agg, W1, b1, out);

    k_agg<<<(Nn + 3) / 4, 256, 0, stream>>>(out, offs, bucket, agg);
    k_layer<false><<<(Nn + 63) / 64, 256, 0, stream>>>(out, agg, W2, b2, out);
}

// Round 3
// 394.125 us; speedup vs baseline: 2.1293x; 1.6297x over previous
//
#include <hip/hip_runtime.h>

#define Nn 50000
#define Dd 128
#define Cc 300

#define BIN_SHIFT 7
#define BIN_W (1 << BIN_SHIFT)
#define NBINS ((Nn + BIN_W - 1) >> BIN_SHIFT)
#define CAP 8192
#define CHUNK 8192

typedef __bf16 bf16_t;
typedef bf16_t bf16x8 __attribute__((ext_vector_type(8)));
typedef float f32x4 __attribute__((ext_vector_type(4)));
typedef unsigned u32x4 __attribute__((ext_vector_type(4)));
typedef unsigned u32x2 __attribute__((ext_vector_type(2)));

__device__ __forceinline__ float lrelu(float x) { return x > 0.f ? x : 0.1f * x; }

__device__ __forceinline__ unsigned f2bf(float f) {
    unsigned u = __builtin_bit_cast(unsigned, f);
    return (u + 0x7fffu + ((u >> 16) & 1u)) >> 16;   // RNE
}
__device__ __forceinline__ unsigned pack2(float a, float b) {
    return f2bf(a) | (f2bf(b) << 16);
}
__device__ __forceinline__ float bflo(unsigned v) {
    return __builtin_bit_cast(float, v << 16);
}
__device__ __forceinline__ float bfhi(unsigned v) {
    return __builtin_bit_cast(float, v & 0xffff0000u);
}

// ---------------- CSR build via two-level counting sort ----------------

__global__ __launch_bounds__(256) void k_bincount(const int* __restrict__ edst,
                                                  int* __restrict__ binCount, int ET) {
    __shared__ int h[NBINS];
    for (int i = threadIdx.x; i < NBINS; i += 256) h[i] = 0;
    __syncthreads();
    for (int i = blockIdx.x * 256 + threadIdx.x; i < ET; i += gridDim.x * 256)
        atomicAdd(&h[edst[i] >> BIN_SHIFT], 1);
    __syncthreads();
    for (int i = threadIdx.x; i < NBINS; i += 256)
        if (h[i]) atomicAdd(&binCount[i], h[i]);
}

__global__ __launch_bounds__(512) void k_binscan(const int* __restrict__ binCount,
                                                 int* __restrict__ binBase,
                                                 int* __restrict__ binCursor,
                                                 int* __restrict__ offs, int ET) {
    __shared__ int wsum[8];
    int tid = threadIdx.x, lane = tid & 63, wid = tid >> 6;
    int v = (tid < NBINS) ? binCount[tid] : 0;
    int incl = v;
    #pragma unroll
    for (int off = 1; off < 64; off <<= 1) {
        int t = __shfl_up(incl, off, 64);
        if (lane >= off) incl += t;
    }
    if (lane == 63) wsum[wid] = incl;
    __syncthreads();
    if (tid == 0) {
        int run = 0;
        #pragma unroll
        for (int w = 0; w < 8; ++w) { int t = wsum[w]; wsum[w] = run; run += t; }
    }
    __syncthreads();
    int excl = wsum[wid] + incl - v;
    if (tid < NBINS) { binBase[tid] = excl; binCursor[tid] = excl; }
    if (tid == NBINS) binBase[NBINS] = excl;
    if (tid == 0) offs[Nn] = ET;
}

__global__ __launch_bounds__(256) void k_binscatter(const int* __restrict__ esrc,
                                                    const int* __restrict__ edst,
                                                    int* __restrict__ binCursor,
                                                    uint2* __restrict__ pairs, int ET) {
    __shared__ int hist[NBINS];
    __shared__ int base[NBINS];
    __shared__ int ssrc[CHUNK];
    __shared__ int sdst[CHUNK];
    int c0 = blockIdx.x * CHUNK;
    int n = min(CHUNK, ET - c0);
    for (int i = threadIdx.x; i < NBINS; i += 256) hist[i] = 0;
    __syncthreads();
    for (int i = threadIdx.x; i < n; i += 256) {
        int s = esrc[c0 + i], d = edst[c0 + i];
        ssrc[i] = s; sdst[i] = d;
        atomicAdd(&hist[d >> BIN_SHIFT], 1);
    }
    __syncthreads();
    for (int i = threadIdx.x; i < NBINS; i += 256) {
        int c = hist[i];
        base[i] = c ? atomicAdd(&binCursor[i], c) : 0;
        hist[i] = 0;
    }
    __syncthreads();
    for (int i = threadIdx.x; i < n; i += 256) {
        int d = sdst[i];
        int b = d >> BIN_SHIFT;
        int p = base[b] + atomicAdd(&hist[b], 1);
        pairs[p] = make_uint2((unsigned)ssrc[i], (unsigned)d);
    }
}

__global__ __launch_bounds__(256) void k_binsort(const uint2* __restrict__ pairs,
                                                 const int* __restrict__ binBase,
                                                 int* __restrict__ offs,
                                                 int* __restrict__ bucket) {
    __shared__ int cnt[BIN_W];
    __shared__ int cur[BIN_W];
    __shared__ int srcbuf[CAP];
    __shared__ int w0sum;
    int bin = blockIdx.x;
    int e0 = binBase[bin], e1 = binBase[bin + 1];
    int n = e1 - e0;
    int tid = threadIdx.x;
    if (tid < BIN_W) cnt[tid] = 0;
    __syncthreads();
    const uint2* p2 = pairs + e0;
    for (int i = tid; i < n; i += 256)
        atomicAdd(&cnt[p2[i].y & (BIN_W - 1)], 1);
    __syncthreads();
    int v = 0, incl = 0;
    if (tid < BIN_W) {
        v = cnt[tid];
        incl = v;
        #pragma unroll
        for (int off = 1; off < 64; off <<= 1) {
            int t = __shfl_up(incl, off, 64);
            if ((tid & 63) >= off) incl += t;
        }
    }
    if (tid == 63) w0sum = incl;
    __syncthreads();
    if (tid < BIN_W) {
        int excl = incl - v + (tid >= 64 ? w0sum : 0);
        cur[tid] = excl;
        int node = (bin << BIN_SHIFT) + tid;
        if (node < Nn) offs[node] = e0 + excl;
    }
    __syncthreads();
    for (int i = tid; i < n; i += 256) {
        uint2 pr = p2[i];
        int p = atomicAdd(&cur[pr.y & (BIN_W - 1)], 1);
        if (p < CAP) srcbuf[p] = (int)pr.x;
    }
    __syncthreads();
    for (int i = tid; i < n; i += 256) bucket[e0 + i] = srcbuf[i];
}

// ---------------- neighbor aggregation on bf16 h ----------------

__global__ __launch_bounds__(256) void k_agg(const unsigned short* __restrict__ h,
                                             const int* __restrict__ offs,
                                             const int* __restrict__ bucket,
                                             unsigned short* __restrict__ agg) {
    int node = blockIdx.x * 4 + (threadIdx.x >> 6);
    if (node >= Nn) return;
    int lane = threadIdx.x & 63;
    const unsigned* h1 = (const unsigned*)h;   // 2 bf16 per word, 64 words/row
    int s = offs[node], e = offs[node + 1];
    float ax = 0.f, ay = 0.f;
    int p = s;
    for (; p + 4 <= e; p += 4) {
        int s0 = bucket[p], s1 = bucket[p + 1], s2 = bucket[p + 2], s3 = bucket[p + 3];
        unsigned v0 = h1[(size_t)s0 * 64 + lane];
        unsigned v1 = h1[(size_t)s1 * 64 + lane];
        unsigned v2 = h1[(size_t)s2 * 64 + lane];
        unsigned v3 = h1[(size_t)s3 * 64 + lane];
        ax += (bflo(v0) + bflo(v1)) + (bflo(v2) + bflo(v3));
        ay += (bfhi(v0) + bfhi(v1)) + (bfhi(v2) + bfhi(v3));
    }
    for (; p < e; ++p) {
        unsigned v0 = h1[(size_t)bucket[p] * 64 + lane];
        ax += bflo(v0);
        ay += bfhi(v0);
    }
    unsigned self = h1[(size_t)node * 64 + lane];
    float inv = 1.f / fmaxf((float)(e - s) - 1.f, 1.f);
    ax = (ax - bflo(self)) * inv;
    ay = (ay - bfhi(self)) * inv;
    ((unsigned*)agg)[(size_t)node * 64 + lane] = pack2(ax, ay);
}

// ---------------- MFMA GEMM helpers ----------------
// LDS tiles: row-major [rows][64 bf16] = 128B rows, granule (16B) XOR-swizzled by row&7.
// Frag (16x16x32): lane l holds row/col (l&15), k = (l>>4)*8 + j  (ks = 0,1 per BK=64).

__device__ __forceinline__ bf16x8 ldfrag(const unsigned short* sm, int row, int ks, int lg) {
    unsigned g = (unsigned)((ks * 4 + lg) ^ (row & 7));
    return __builtin_bit_cast(bf16x8, *(const u32x4*)(sm + row * 64 + g * 8));
}
__device__ __forceinline__ void st8(unsigned short* sm, int row, int c4, unsigned lo, unsigned hi) {
    unsigned off = (unsigned)row * 64 + ((((unsigned)c4 >> 1) ^ (row & 7)) << 3) + ((c4 & 1) << 2);
    *(u32x2*)(sm + off) = (u32x2){lo, hi};
}

// ---------------- h0 = emb[i+1] + lrelu(content @ projW^T + b) : bf16 out ----------------

__global__ __launch_bounds__(256) void k_h0(const float* __restrict__ content,
                                            const float* __restrict__ projW,
                                            const float* __restrict__ projB,
                                            const float* __restrict__ emb,
                                            unsigned short* __restrict__ h) {
    __shared__ unsigned short sA[64 * 64];
    __shared__ unsigned short sB[128 * 64];
    int bm = blockIdx.x * 64;
    int tid = threadIdx.x;
    int wid = tid >> 6, l = tid & 63, lr = l & 15, lg = l >> 4;
    int wm = (wid & 1) * 32, wn = (wid >> 1) * 64;
    f32x4 acc[2][4];
    #pragma unroll
    for (int mf = 0; mf < 2; ++mf)
        #pragma unroll
        for (int nf = 0; nf < 4; ++nf) acc[mf][nf] = (f32x4){0.f, 0.f, 0.f, 0.f};

    for (int k0 = 0; k0 < 320; k0 += 64) {
        for (int idx = tid; idx < 64 * 16; idx += 256) {
            int r = idx >> 4, c4 = idx & 15;
            int gi = bm + r, k = k0 + c4 * 4;
            float4 v = make_float4(0.f, 0.f, 0.f, 0.f);
            if (gi < Nn && k < Cc) v = *(const float4*)(content + (size_t)gi * Cc + k);
            st8(sA, r, c4, pack2(v.x, v.y), pack2(v.z, v.w));
        }
        for (int idx = tid; idx < 128 * 16; idx += 256) {
            int r = idx >> 4, c4 = idx & 15;
            int k = k0 + c4 * 4;
            float4 v = make_float4(0.f, 0.f, 0.f, 0.f);
            if (k < Cc) v = *(const float4*)(projW + (size_t)r * Cc + k);
            st8(sB, r, c4, pack2(v.x, v.y), pack2(v.z, v.w));
        }
        __syncthreads();
        #pragma unroll
        for (int ks = 0; ks < 2; ++ks) {
            bf16x8 a[2], b[4];
            #pragma unroll
            for (int mf = 0; mf < 2; ++mf) a[mf] = ldfrag(sA, wm + mf * 16 + lr, ks, lg);
            #pragma unroll
            for (int nf = 0; nf < 4; ++nf) b[nf] = ldfrag(sB, wn + nf * 16 + lr, ks, lg);
            #pragma unroll
            for (int mf = 0; mf < 2; ++mf)
                #pragma unroll
                for (int nf = 0; nf < 4; ++nf)
                    acc[mf][nf] = __builtin_amdgcn_mfma_f32_16x16x32_bf16(a[mf], b[nf], acc[mf][nf], 0, 0, 0);
        }
        __syncthreads();
    }

    float pb[4];
    #pragma unroll
    for (int nf = 0; nf < 4; ++nf) pb[nf] = projB[wn + nf * 16 + lr];
    #pragma unroll
    for (int mf = 0; mf < 2; ++mf)
        #pragma unroll
        for (int v = 0; v < 4; ++v) {
            int row = bm + wm + mf * 16 + lg * 4 + v;
            if (row >= Nn) continue;
            #pragma unroll
            for (int nf = 0; nf < 4; ++nf) {
                int col = wn + nf * 16 + lr;
                float x = lrelu(acc[mf][nf][v] + pb[nf]) + emb[(size_t)(row + 1) * Dd + col];
                h[(size_t)row * Dd + col] = (unsigned short)f2bf(x);
            }
        }
}

// ---------------- SAGE layer: rownorm(act(concat(h,agg) @ W^T + b)) ----------------
// MODE 0: lrelu act, bf16 output. MODE 1: no act, fp32 output.

template <int MODE>
__global__ __launch_bounds__(256) void k_layer(const unsigned short* __restrict__ hsrc,
                                               const unsigned short* __restrict__ asrc,
                                               const float* __restrict__ W,
                                               const float* __restrict__ bias,
                                               void* __restrict__ outp) {
    __shared__ unsigned short sA[64 * 64];
    __shared__ unsigned short sB[128 * 64];
    __shared__ float rowsum[64];
    int bm = blockIdx.x * 64;
    int tid = threadIdx.x;
    int wid = tid >> 6, l = tid & 63, lr = l & 15, lg = l >> 4;
    int wm = (wid & 1) * 32, wn = (wid >> 1) * 64;
    if (tid < 64) rowsum[tid] = 0.f;
    f32x4 acc[2][4];
    #pragma unroll
    for (int mf = 0; mf < 2; ++mf)
        #pragma unroll
        for (int nf = 0; nf < 4; ++nf) acc[mf][nf] = (f32x4){0.f, 0.f, 0.f, 0.f};

    for (int kc = 0; kc < 4; ++kc) {
        const unsigned short* Asrc = (kc < 2) ? hsrc : asrc;
        int koff = (kc & 1) * 64;
        for (int idx = tid; idx < 64 * 8; idx += 256) {
            int r = idx >> 3, g = idx & 7;
            int gi = bm + r;
            u32x4 v = (u32x4){0u, 0u, 0u, 0u};
            if (gi < Nn) v = *(const u32x4*)(Asrc + (size_t)gi * Dd + koff + g * 8);
            unsigned gg = (unsigned)g ^ (r & 7);
            *(u32x4*)(sA + r * 64 + gg * 8) = v;
        }
        for (int idx = tid; idx < 128 * 16; idx += 256) {
            int r = idx >> 4, c4 = idx & 15;
            int k = kc * 64 + c4 * 4;
            float4 v = *(const float4*)(W + (size_t)r * 256 + k);
            st8(sB, r, c4, pack2(v.x, v.y), pack2(v.z, v.w));
        }
        __syncthreads();
        #pragma unroll
        for (int ks = 0; ks < 2; ++ks) {
            bf16x8 a[2], b[4];
            #pragma unroll
            for (int mf = 0; mf < 2; ++mf) a[mf] = ldfrag(sA, wm + mf * 16 + lr, ks, lg);
            #pragma unroll
            for (int nf = 0; nf < 4; ++nf) b[nf] = ldfrag(sB, wn + nf * 16 + lr, ks, lg);
            #pragma unroll
            for (int mf = 0; mf < 2; ++mf)
                #pragma unroll
                for (int nf = 0; nf < 4; ++nf)
                    acc[mf][nf] = __builtin_amdgcn_mfma_f32_16x16x32_bf16(a[mf], b[nf], acc[mf][nf], 0, 0, 0);
        }
        __syncthreads();
    }

    float pb[4];
    #pragma unroll
    for (int nf = 0; nf < 4; ++nf) pb[nf] = bias[wn + nf * 16 + lr];
    float ps[2][4];
    #pragma unroll
    for (int mf = 0; mf < 2; ++mf)
        #pragma unroll
        for (int v = 0; v < 4; ++v) {
            float s = 0.f;
            #pragma unroll
            for (int nf = 0; nf < 4; ++nf) {
                float x = acc[mf][nf][v] + pb[nf];
                if (MODE == 0) x = lrelu(x);
                acc[mf][nf][v] = x;
                s += x * x;
            }
            ps[mf][v] = s;
        }
    #pragma unroll
    for (int off = 1; off < 16; off <<= 1)
        #pragma unroll
        for (int mf = 0; mf < 2; ++mf)
            #pragma unroll
            for (int v = 0; v < 4; ++v) ps[mf][v] += __shfl_xor(ps[mf][v], off, 16);
    if (lr == 0) {
        #pragma unroll
        for (int mf = 0; mf < 2; ++mf)
            #pragma unroll
            for (int v = 0; v < 4; ++v)
                atomicAdd(&rowsum[wm + mf * 16 + lg * 4 + v], ps[mf][v]);
    }
    __syncthreads();
    #pragma unroll
    for (int mf = 0; mf < 2; ++mf)
        #pragma unroll
        for (int v = 0; v < 4; ++v) {
            int row = bm + wm + mf * 16 + lg * 4 + v;
            if (row >= Nn) continue;
            float inv = 1.f / fmaxf(sqrtf(rowsum[wm + mf * 16 + lg * 4 + v]), 1e-6f);
            #pragma unroll
            for (int nf = 0; nf < 4; ++nf) {
                int col = wn + nf * 16 + lr;
                float x = acc[mf][nf][v] * inv;
                if (MODE == 0)
                    ((unsigned short*)outp)[(size_t)row * Dd + col] = (unsigned short)f2bf(x);
                else
                    ((float*)outp)[(size_t)row * Dd + col] = x;
            }
        }
}

// ---------------- launch ----------------

extern "C" void kernel_launch(void* const* d_in, const int* in_sizes, int n_in,
                              void* d_out, int out_size, void* d_ws, size_t ws_size,
                              hipStream_t stream) {
    const float* node_emb = (const float*)d_in[0];
    const float* content  = (const float*)d_in[1];
    const float* projW    = (const float*)d_in[2];
    const float* projB    = (const float*)d_in[3];
    const float* W1 = (const float*)d_in[4];
    const float* b1 = (const float*)d_in[5];
    const float* W2 = (const float*)d_in[6];
    const float* b2 = (const float*)d_in[7];
    const int* esrc = (const int*)d_in[8];
    const int* edst = (const int*)d_in[9];
    const int ET = in_sizes[8];
    float* out = (float*)d_out;

    // workspace layout
    unsigned short* h0  = (unsigned short*)d_ws;          // N*128 bf16
    unsigned short* h1  = h0 + (size_t)Nn * Dd;           // N*128 bf16
    unsigned short* agg = h1 + (size_t)Nn * Dd;           // N*128 bf16
    int* offs      = (int*)(agg + (size_t)Nn * Dd);       // N+1
    int* binCount  = offs + Nn + 1;
    int* binBase   = binCount + NBINS;
    int* binCursor = binBase + NBINS + 1;
    int* bucket    = binCursor + NBINS;                   // ET
    uintptr_t pa = (uintptr_t)(bucket + ET);
    pa = (pa + 15) & ~(uintptr_t)15;
    uint2* pairs = (uint2*)pa;                            // ET * 8B

    hipMemsetAsync(binCount, 0, NBINS * sizeof(int), stream);
    k_bincount<<<256, 256, 0, stream>>>(edst, binCount, ET);
    k_binscan<<<1, 512, 0, stream>>>(binCount, binBase, binCursor, offs, ET);
    k_binscatter<<<(ET + CHUNK - 1) / CHUNK, 256, 0, stream>>>(esrc, edst, binCursor, pairs, ET);
    k_binsort<<<NBINS, 256, 0, stream>>>(pairs, binBase, offs, bucket);

    k_h0<<<(Nn + 63) / 64, 256, 0, stream>>>(content, projW, projB, node_emb, h0);

    k_agg<<<(Nn + 3) / 4, 256, 0, stream>>>(h0, offs, bucket, agg);
    k_layer<0><<<(Nn + 63) / 64, 256, 0, stream>>>(h0, agg, W1, b1, (void*)h1);

    k_agg<<<(Nn + 3) / 4, 256, 0, stream>>>(h1, offs, bucket, agg);
    k_layer<1><<<(Nn + 63) / 64, 256, 0, stream>>>(h1, agg, W2, b2, (void*)out);
}

// Round 5
// 393.073 us; speedup vs baseline: 2.1350x; 1.0027x over previous
//
#include <hip/hip_runtime.h>

#define Nn 50000
#define Dd 128
#define Cc 300

#define BIN_SHIFT 7
#define BIN_W (1 << BIN_SHIFT)
#define NBINS ((Nn + BIN_W - 1) >> BIN_SHIFT)    // 391
#define CAP 5120                                  // per-bin capacity (mean 4224, sigma ~65)
#define CHUNK 8192

typedef __bf16 bf16_t;
typedef bf16_t bf16x8 __attribute__((ext_vector_type(8)));
typedef float f32x4 __attribute__((ext_vector_type(4)));
typedef unsigned u32x4 __attribute__((ext_vector_type(4)));
typedef unsigned u32x2 __attribute__((ext_vector_type(2)));

__device__ __forceinline__ float lrelu(float x) { return x > 0.f ? x : 0.1f * x; }

__device__ __forceinline__ unsigned f2bf(float f) {
    unsigned u = __builtin_bit_cast(unsigned, f);
    return (u + 0x7fffu + ((u >> 16) & 1u)) >> 16;   // RNE
}
__device__ __forceinline__ unsigned pack2(float a, float b) {
    return f2bf(a) | (f2bf(b) << 16);
}
__device__ __forceinline__ float bflo(unsigned v) {
    return __builtin_bit_cast(float, v << 16);
}
__device__ __forceinline__ float bfhi(unsigned v) {
    return __builtin_bit_cast(float, v & 0xffff0000u);
}

// ---------------- edge binning: packed u32 = src(16b) | local7(7b)<<16 | bin(9b)<<23 ------

__global__ __launch_bounds__(256) void k_binscatter(const int* __restrict__ esrc,
                                                    const int* __restrict__ edst,
                                                    int* __restrict__ binCursor,
                                                    unsigned* __restrict__ pairs, int ET) {
    __shared__ int hist[NBINS];
    __shared__ int base[NBINS];
    __shared__ unsigned spk[CHUNK];
    int c0 = blockIdx.x * CHUNK;
    int n = min(CHUNK, ET - c0);
    for (int i = threadIdx.x; i < NBINS; i += 256) hist[i] = 0;
    __syncthreads();
    for (int i = threadIdx.x; i < n; i += 256) {
        unsigned s = (unsigned)esrc[c0 + i];
        unsigned d = (unsigned)edst[c0 + i];
        spk[i] = s | ((d & (BIN_W - 1)) << 16) | ((d >> BIN_SHIFT) << 23);
        atomicAdd(&hist[d >> BIN_SHIFT], 1);
    }
    __syncthreads();
    for (int i = threadIdx.x; i < NBINS; i += 256) {
        int c = hist[i];
        base[i] = c ? atomicAdd(&binCursor[i], c) : 0;
        hist[i] = 0;  // reuse as local cursor
    }
    __syncthreads();
    for (int i = threadIdx.x; i < n; i += 256) {
        unsigned v = spk[i];
        int b = v >> 23;
        int pos = base[b] + atomicAdd(&hist[b], 1);
        if (pos < CAP)
            __builtin_nontemporal_store(v & 0x7fffffu, &pairs[(size_t)b * CAP + pos]);
    }
}

__global__ __launch_bounds__(256) void k_binsort(const unsigned* __restrict__ pairs,
                                                 const int* __restrict__ binCursor,
                                                 int* __restrict__ offs,
                                                 int* __restrict__ deg,
                                                 int* __restrict__ bucket) {
    __shared__ int cnt[BIN_W];
    __shared__ int cur[BIN_W];
    __shared__ int srcbuf[CAP];
    __shared__ int w0sum;
    int bin = blockIdx.x;
    int e0 = bin * CAP;
    int n = min(binCursor[bin], CAP);
    int tid = threadIdx.x;
    if (tid < BIN_W) cnt[tid] = 0;
    __syncthreads();
    const unsigned* p2 = pairs + e0;
    for (int i = tid; i < n; i += 256)
        atomicAdd(&cnt[p2[i] >> 16], 1);
    __syncthreads();
    int v = 0, incl = 0;
    if (tid < BIN_W) {
        v = cnt[tid];
        incl = v;
        #pragma unroll
        for (int off = 1; off < 64; off <<= 1) {
            int t = __shfl_up(incl, off, 64);
            if ((tid & 63) >= off) incl += t;
        }
    }
    if (tid == 63) w0sum = incl;
    __syncthreads();
    if (tid < BIN_W) {
        int excl = incl - v + (tid >= 64 ? w0sum : 0);
        cur[tid] = excl;
        int node = (bin << BIN_SHIFT) + tid;
        if (node < Nn) {
            __builtin_nontemporal_store(e0 + excl, &offs[node]);
            __builtin_nontemporal_store(v, &deg[node]);
        }
    }
    __syncthreads();
    for (int i = tid; i < n; i += 256) {
        unsigned pr = p2[i];
        int p = atomicAdd(&cur[pr >> 16], 1);
        if (p < CAP) srcbuf[p] = (int)(pr & 0xffffu);
    }
    __syncthreads();
    for (int i = tid; i < n; i += 256)
        __builtin_nontemporal_store(srcbuf[i], &bucket[e0 + i]);
}

// ---------------- neighbor aggregation on bf16 h ----------------
// Wave per node; neighbor ids prefetched coalesced, broadcast via shfl -> only the
// h-row gathers touch global memory inside the loop, 8 in flight.

__global__ __launch_bounds__(256) void k_agg(const unsigned short* __restrict__ h,
                                             const int* __restrict__ offs,
                                             const int* __restrict__ deg,
                                             const int* __restrict__ bucket,
                                             unsigned short* __restrict__ agg) {
    int node = blockIdx.x * 4 + (threadIdx.x >> 6);
    if (node >= Nn) return;
    int lane = threadIdx.x & 63;
    const unsigned* h1 = (const unsigned*)h;   // 2 bf16 per word, 64 words/row
    int s = offs[node], d = deg[node];
    float ax = 0.f, ay = 0.f;
    for (int base = 0; base < d; base += 64) {
        int nrem = min(64, d - base);
        int myid = 0;
        if (base + lane < d) myid = bucket[s + base + lane];
        int j = 0;
        for (; j + 8 <= nrem; j += 8) {
            int i0 = __shfl(myid, j + 0), i1 = __shfl(myid, j + 1);
            int i2 = __shfl(myid, j + 2), i3 = __shfl(myid, j + 3);
            int i4 = __shfl(myid, j + 4), i5 = __shfl(myid, j + 5);
            int i6 = __shfl(myid, j + 6), i7 = __shfl(myid, j + 7);
            unsigned v0 = h1[(size_t)i0 * 64 + lane];
            unsigned v1 = h1[(size_t)i1 * 64 + lane];
            unsigned v2 = h1[(size_t)i2 * 64 + lane];
            unsigned v3 = h1[(size_t)i3 * 64 + lane];
            unsigned v4 = h1[(size_t)i4 * 64 + lane];
            unsigned v5 = h1[(size_t)i5 * 64 + lane];
            unsigned v6 = h1[(size_t)i6 * 64 + lane];
            unsigned v7 = h1[(size_t)i7 * 64 + lane];
            ax += ((bflo(v0) + bflo(v1)) + (bflo(v2) + bflo(v3))) +
                  ((bflo(v4) + bflo(v5)) + (bflo(v6) + bflo(v7)));
            ay += ((bfhi(v0) + bfhi(v1)) + (bfhi(v2) + bfhi(v3))) +
                  ((bfhi(v4) + bfhi(v5)) + (bfhi(v6) + bfhi(v7)));
        }
        for (; j < nrem; ++j) {
            int id = __shfl(myid, j);
            unsigned v = h1[(size_t)id * 64 + lane];
            ax += bflo(v);
            ay += bfhi(v);
        }
    }
    unsigned self = h1[(size_t)node * 64 + lane];
    float inv = 1.f / fmaxf((float)d - 1.f, 1.f);
    ax = (ax - bflo(self)) * inv;
    ay = (ay - bfhi(self)) * inv;
    __builtin_nontemporal_store(pack2(ax, ay), &((unsigned*)agg)[(size_t)node * 64 + lane]);
}

// ---------------- MFMA GEMM helpers ----------------

__device__ __forceinline__ bf16x8 ldfrag(const unsigned short* sm, int row, int ks, int lg) {
    unsigned g = (unsigned)((ks * 4 + lg) ^ (row & 7));
    return __builtin_bit_cast(bf16x8, *(const u32x4*)(sm + row * 64 + g * 8));
}
__device__ __forceinline__ void st8(unsigned short* sm, int row, int c4, unsigned lo, unsigned hi) {
    unsigned off = (unsigned)row * 64 + ((((unsigned)c4 >> 1) ^ (row & 7)) << 3) + ((c4 & 1) << 2);
    *(u32x2*)(sm + off) = (u32x2){lo, hi};
}

// ---------------- h0 = emb[i+1] + lrelu(content @ projW^T + b) : bf16 out ----------------

__global__ __launch_bounds__(256) void k_h0(const float* __restrict__ content,
                                            const float* __restrict__ projW,
                                            const float* __restrict__ projB,
                                            const float* __restrict__ emb,
                                            unsigned short* __restrict__ h) {
    __shared__ unsigned short sA[64 * 64];
    __shared__ unsigned short sB[128 * 64];
    int bm = blockIdx.x * 64;
    int tid = threadIdx.x;
    int wid = tid >> 6, l = tid & 63, lr = l & 15, lg = l >> 4;
    int wm = (wid & 1) * 32, wn = (wid >> 1) * 64;
    f32x4 acc[2][4];
    #pragma unroll
    for (int mf = 0; mf < 2; ++mf)
        #pragma unroll
        for (int nf = 0; nf < 4; ++nf) acc[mf][nf] = (f32x4){0.f, 0.f, 0.f, 0.f};

    for (int k0 = 0; k0 < 320; k0 += 64) {
        for (int idx = tid; idx < 64 * 16; idx += 256) {
            int r = idx >> 4, c4 = idx & 15;
            int gi = bm + r, k = k0 + c4 * 4;
            float4 v = make_float4(0.f, 0.f, 0.f, 0.f);
            if (gi < Nn && k < Cc) v = *(const float4*)(content + (size_t)gi * Cc + k);
            st8(sA, r, c4, pack2(v.x, v.y), pack2(v.z, v.w));
        }
        for (int idx = tid; idx < 128 * 16; idx += 256) {
            int r = idx >> 4, c4 = idx & 15;
            int k = k0 + c4 * 4;
            float4 v = make_float4(0.f, 0.f, 0.f, 0.f);
            if (k < Cc) v = *(const float4*)(projW + (size_t)r * Cc + k);
            st8(sB, r, c4, pack2(v.x, v.y), pack2(v.z, v.w));
        }
        __syncthreads();
        #pragma unroll
        for (int ks = 0; ks < 2; ++ks) {
            bf16x8 a[2], b[4];
            #pragma unroll
            for (int mf = 0; mf < 2; ++mf) a[mf] = ldfrag(sA, wm + mf * 16 + lr, ks, lg);
            #pragma unroll
            for (int nf = 0; nf < 4; ++nf) b[nf] = ldfrag(sB, wn + nf * 16 + lr, ks, lg);
            #pragma unroll
            for (int mf = 0; mf < 2; ++mf)
                #pragma unroll
                for (int nf = 0; nf < 4; ++nf)
                    acc[mf][nf] = __builtin_amdgcn_mfma_f32_16x16x32_bf16(a[mf], b[nf], acc[mf][nf], 0, 0, 0);
        }
        __syncthreads();
    }

    float pb[4];
    #pragma unroll
    for (int nf = 0; nf < 4; ++nf) pb[nf] = projB[wn + nf * 16 + lr];
    #pragma unroll
    for (int mf = 0; mf < 2; ++mf)
        #pragma unroll
        for (int v = 0; v < 4; ++v) {
            int row = bm + wm + mf * 16 + lg * 4 + v;
            if (row >= Nn) continue;
            #pragma unroll
            for (int nf = 0; nf < 4; ++nf) {
                int col = wn + nf * 16 + lr;
                float x = lrelu(acc[mf][nf][v] + pb[nf]) + emb[(size_t)(row + 1) * Dd + col];
                h[(size_t)row * Dd + col] = (unsigned short)f2bf(x);
            }
        }
}

// ---------------- SAGE layer: rownorm(act(concat(h,agg) @ W^T + b)) ----------------

template <int MODE>
__global__ __launch_bounds__(256) void k_layer(const unsigned short* __restrict__ hsrc,
                                               const unsigned short* __restrict__ asrc,
                                               const float* __restrict__ W,
                                               const float* __restrict__ bias,
                                               void* __restrict__ outp) {
    __shared__ unsigned short sA[64 * 64];
    __shared__ unsigned short sB[128 * 64];
    __shared__ float rowsum[64];
    int bm = blockIdx.x * 64;
    int tid = threadIdx.x;
    int wid = tid >> 6, l = tid & 63, lr = l & 15, lg = l >> 4;
    int wm = (wid & 1) * 32, wn = (wid >> 1) * 64;
    if (tid < 64) rowsum[tid] = 0.f;
    f32x4 acc[2][4];
    #pragma unroll
    for (int mf = 0; mf < 2; ++mf)
        #pragma unroll
        for (int nf = 0; nf < 4; ++nf) acc[mf][nf] = (f32x4){0.f, 0.f, 0.f, 0.f};

    for (int kc = 0; kc < 4; ++kc) {
        const unsigned short* Asrc = (kc < 2) ? hsrc : asrc;
        int koff = (kc & 1) * 64;
        for (int idx = tid; idx < 64 * 8; idx += 256) {
            int r = idx >> 3, g = idx & 7;
            int gi = bm + r;
            u32x4 v = (u32x4){0u, 0u, 0u, 0u};
            if (gi < Nn) v = *(const u32x4*)(Asrc + (size_t)gi * Dd + koff + g * 8);
            unsigned gg = (unsigned)g ^ (r & 7);
            *(u32x4*)(sA + r * 64 + gg * 8) = v;
        }
        for (int idx = tid; idx < 128 * 16; idx += 256) {
            int r = idx >> 4, c4 = idx & 15;
            int k = kc * 64 + c4 * 4;
            float4 v = *(const float4*)(W + (size_t)r * 256 + k);
            st8(sB, r, c4, pack2(v.x, v.y), pack2(v.z, v.w));
        }
        __syncthreads();
        #pragma unroll
        for (int ks = 0; ks < 2; ++ks) {
            bf16x8 a[2], b[4];
            #pragma unroll
            for (int mf = 0; mf < 2; ++mf) a[mf] = ldfrag(sA, wm + mf * 16 + lr, ks, lg);
            #pragma unroll
            for (int nf = 0; nf < 4; ++nf) b[nf] = ldfrag(sB, wn + nf * 16 + lr, ks, lg);
            #pragma unroll
            for (int mf = 0; mf < 2; ++mf)
                #pragma unroll
                for (int nf = 0; nf < 4; ++nf)
                    acc[mf][nf] = __builtin_amdgcn_mfma_f32_16x16x32_bf16(a[mf], b[nf], acc[mf][nf], 0, 0, 0);
        }
        __syncthreads();
    }

    float pb[4];
    #pragma unroll
    for (int nf = 0; nf < 4; ++nf) pb[nf] = bias[wn + nf * 16 + lr];
    float ps[2][4];
    #pragma unroll
    for (int mf = 0; mf < 2; ++mf)
        #pragma unroll
        for (int v = 0; v < 4; ++v) {
            float s = 0.f;
            #pragma unroll
            for (int nf = 0; nf < 4; ++nf) {
                float x = acc[mf][nf][v] + pb[nf];
                if (MODE == 0) x = lrelu(x);
                acc[mf][nf][v] = x;
                s += x * x;
            }
            ps[mf][v] = s;
        }
    #pragma unroll
    for (int off = 1; off < 16; off <<= 1)
        #pragma unroll
        for (int mf = 0; mf < 2; ++mf)
            #pragma unroll
            for (int v = 0; v < 4; ++v) ps[mf][v] += __shfl_xor(ps[mf][v], off, 16);
    if (lr == 0) {
        #pragma unroll
        for (int mf = 0; mf < 2; ++mf)
            #pragma unroll
            for (int v = 0; v < 4; ++v)
                atomicAdd(&rowsum[wm + mf * 16 + lg * 4 + v], ps[mf][v]);
    }
    __syncthreads();
    #pragma unroll
    for (int mf = 0; mf < 2; ++mf)
        #pragma unroll
        for (int v = 0; v < 4; ++v) {
            int row = bm + wm + mf * 16 + lg * 4 + v;
            if (row >= Nn) continue;
            float inv = 1.f / fmaxf(sqrtf(rowsum[wm + mf * 16 + lg * 4 + v]), 1e-6f);
            #pragma unroll
            for (int nf = 0; nf < 4; ++nf) {
                int col = wn + nf * 16 + lr;
                float x = acc[mf][nf][v] * inv;
                if (MODE == 0)
                    ((unsigned short*)outp)[(size_t)row * Dd + col] = (unsigned short)f2bf(x);
                else
                    ((float*)outp)[(size_t)row * Dd + col] = x;
            }
        }
}

// ---------------- launch ----------------

extern "C" void kernel_launch(void* const* d_in, const int* in_sizes, int n_in,
                              void* d_out, int out_size, void* d_ws, size_t ws_size,
                              hipStream_t stream) {
    const float* node_emb = (const float*)d_in[0];
    const float* content  = (const float*)d_in[1];
    const float* projW    = (const float*)d_in[2];
    const float* projB    = (const float*)d_in[3];
    const float* W1 = (const float*)d_in[4];
    const float* b1 = (const float*)d_in[5];
    const float* W2 = (const float*)d_in[6];
    const float* b2 = (const float*)d_in[7];
    const int* esrc = (const int*)d_in[8];
    const int* edst = (const int*)d_in[9];
    const int ET = in_sizes[8];
    float* out = (float*)d_out;

    // workspace layout (~55 MB)
    unsigned short* h0  = (unsigned short*)d_ws;          // N*128 bf16
    unsigned short* h1  = h0 + (size_t)Nn * Dd;           // N*128 bf16
    unsigned short* agg = h1 + (size_t)Nn * Dd;           // N*128 bf16
    int* offs      = (int*)(agg + (size_t)Nn * Dd);       // N
    int* deg       = offs + Nn;                           // N
    int* binCursor = deg + Nn;                            // NBINS
    int* bucket    = binCursor + NBINS;                   // NBINS*CAP
    unsigned* pairs = (unsigned*)(bucket + (size_t)NBINS * CAP);  // NBINS*CAP

    hipMemsetAsync(binCursor, 0, NBINS * sizeof(int), stream);
    k_binscatter<<<(ET + CHUNK - 1) / CHUNK, 256, 0, stream>>>(esrc, edst, binCursor, pairs, ET);
    k_binsort<<<NBINS, 256, 0, stream>>>(pairs, binCursor, offs, deg, bucket);

    k_h0<<<(Nn + 63) / 64, 256, 0, stream>>>(content, projW, projB, node_emb, h0);

    k_agg<<<(Nn + 3) / 4, 256, 0, stream>>>(h0, offs, deg, bucket, agg);
    k_layer<0><<<(Nn + 63) / 64, 256, 0, stream>>>(h0, agg, W1, b1, (void*)h1);

    k_agg<<<(Nn + 3) / 4, 256, 0, stream>>>(h1, offs, deg, bucket, agg);
    k_layer<1><<<(Nn + 63) / 64, 256, 0, stream>>>(h1, agg, W2, b2, (void*)out);
}

// Round 6
// 353.596 us; speedup vs baseline: 2.3734x; 1.1116x over previous
//
#include <hip/hip_runtime.h>

#define Nn 50000
#define Dd 128
#define Cc 300

#define BIN_SHIFT 7
#define BIN_W (1 << BIN_SHIFT)
#define NBINS ((Nn + BIN_W - 1) >> BIN_SHIFT)    // 391
#define CAP 5120                                  // per-bin capacity (mean 4224, sigma ~64)
#define SCHUNK 8192

typedef __bf16 bf16_t;
typedef bf16_t bf16x8 __attribute__((ext_vector_type(8)));
typedef float f32x4 __attribute__((ext_vector_type(4)));
typedef unsigned u32x4 __attribute__((ext_vector_type(4)));
typedef unsigned u32x2 __attribute__((ext_vector_type(2)));

__device__ __forceinline__ float lrelu(float x) { return x > 0.f ? x : 0.1f * x; }

__device__ __forceinline__ unsigned f2bf(float f) {
    unsigned u = __builtin_bit_cast(unsigned, f);
    return (u + 0x7fffu + ((u >> 16) & 1u)) >> 16;   // RNE
}
__device__ __forceinline__ unsigned pack2(float a, float b) {
    return f2bf(a) | (f2bf(b) << 16);
}
__device__ __forceinline__ float bflo(unsigned v) {
    return __builtin_bit_cast(float, v << 16);
}
__device__ __forceinline__ float bfhi(unsigned v) {
    return __builtin_bit_cast(float, v & 0xffff0000u);
}

// ---------------- edge binning via block-local LDS counting sort ----------------
// packed u32 = src(16b) | local7(7b)<<16 | bin(9b)<<23; pairs stores low 23 bits.
// All global writes are sequential runs (no partial-line scatter).

__global__ __launch_bounds__(512) void k_binscatter(const int* __restrict__ esrc,
                                                    const int* __restrict__ edst,
                                                    int* __restrict__ binCursor,
                                                    unsigned* __restrict__ pairs, int ET) {
    __shared__ unsigned sorted[SCHUNK];   // 32 KB
    __shared__ int hist[NBINS];
    __shared__ int lbase[NBINS];
    __shared__ int gbase[NBINS];
    __shared__ int wsums[8];
    int tid = threadIdx.x;
    int c0 = blockIdx.x * SCHUNK;
    int n = min(SCHUNK, ET - c0);
    for (int i = tid; i < NBINS; i += 512) hist[i] = 0;
    __syncthreads();
    // pass 1: histogram
    for (int i = tid; i < n; i += 512)
        atomicAdd(&hist[((unsigned)edst[c0 + i]) >> BIN_SHIFT], 1);
    __syncthreads();
    // block scan over NBINS (7 waves), plus global reservation per bin
    {
        int lane = tid & 63, wid = tid >> 6;
        int v = (tid < NBINS) ? hist[tid] : 0;
        int incl = v;
        #pragma unroll
        for (int off = 1; off < 64; off <<= 1) {
            int t = __shfl_up(incl, off, 64);
            if (lane >= off) incl += t;
        }
        if (lane == 63) wsums[wid] = incl;
        __syncthreads();
        if (tid == 0) {
            int run = 0;
            #pragma unroll
            for (int w = 0; w < 8; ++w) { int t = wsums[w]; wsums[w] = run; run += t; }
        }
        __syncthreads();
        if (tid < NBINS) {
            int excl = wsums[wid] + incl - v;
            lbase[tid] = excl;
            gbase[tid] = v ? atomicAdd(&binCursor[tid], v) : 0;
            hist[tid] = 0;  // reuse as local cursor
        }
    }
    __syncthreads();
    // pass 2: permute chunk into bin-sorted LDS order
    for (int i = tid; i < n; i += 512) {
        unsigned s = (unsigned)esrc[c0 + i];
        unsigned d = (unsigned)edst[c0 + i];
        unsigned b = d >> BIN_SHIFT;
        unsigned pk = s | ((d & (BIN_W - 1)) << 16) | (b << 23);
        int pos = lbase[b] + atomicAdd(&hist[b], 1);
        sorted[pos] = pk;
    }
    __syncthreads();
    // pass 3: linear write-out; consecutive i -> consecutive global addresses per run
    for (int i = tid; i < n; i += 512) {
        unsigned pk = sorted[i];
        unsigned b = pk >> 23;
        int idx = gbase[b] + (i - lbase[b]);
        if (idx < CAP)
            pairs[(size_t)b * CAP + idx] = pk & 0x7fffffu;
    }
}

__global__ __launch_bounds__(256) void k_binsort(const unsigned* __restrict__ pairs,
                                                 const int* __restrict__ binCursor,
                                                 int* __restrict__ offs,
                                                 int* __restrict__ deg,
                                                 int* __restrict__ bucket) {
    __shared__ int cnt[BIN_W];
    __shared__ int cur[BIN_W];
    __shared__ int srcbuf[CAP];
    __shared__ int w0sum;
    int bin = blockIdx.x;
    int e0 = bin * CAP;
    int n = min(binCursor[bin], CAP);
    int tid = threadIdx.x;
    if (tid < BIN_W) cnt[tid] = 0;
    __syncthreads();
    const unsigned* p2 = pairs + e0;
    for (int i = tid; i < n; i += 256)
        atomicAdd(&cnt[p2[i] >> 16], 1);
    __syncthreads();
    int v = 0, incl = 0;
    if (tid < BIN_W) {
        v = cnt[tid];
        incl = v;
        #pragma unroll
        for (int off = 1; off < 64; off <<= 1) {
            int t = __shfl_up(incl, off, 64);
            if ((tid & 63) >= off) incl += t;
        }
    }
    if (tid == 63) w0sum = incl;
    __syncthreads();
    if (tid < BIN_W) {
        int excl = incl - v + (tid >= 64 ? w0sum : 0);
        cur[tid] = excl;
        int node = (bin << BIN_SHIFT) + tid;
        if (node < Nn) {
            __builtin_nontemporal_store(e0 + excl, &offs[node]);
            __builtin_nontemporal_store(v, &deg[node]);
        }
    }
    __syncthreads();
    for (int i = tid; i < n; i += 256) {
        unsigned pr = p2[i];
        int p = atomicAdd(&cur[pr >> 16], 1);
        if (p < CAP) srcbuf[p] = (int)(pr & 0xffffu);
    }
    __syncthreads();
    for (int i = tid; i < n; i += 256)
        __builtin_nontemporal_store(srcbuf[i], &bucket[e0 + i]);
}

// ---------------- neighbor aggregation on bf16 h ----------------
// Wave per node; neighbor ids prefetched coalesced, broadcast via shfl -> only the
// h-row gathers touch global memory inside the loop, 8 in flight.

__global__ __launch_bounds__(256) void k_agg(const unsigned short* __restrict__ h,
                                             const int* __restrict__ offs,
                                             const int* __restrict__ deg,
                                             const int* __restrict__ bucket,
                                             unsigned short* __restrict__ agg) {
    int node = blockIdx.x * 4 + (threadIdx.x >> 6);
    if (node >= Nn) return;
    int lane = threadIdx.x & 63;
    const unsigned* h1 = (const unsigned*)h;   // 2 bf16 per word, 64 words/row
    int s = offs[node], d = deg[node];
    float ax = 0.f, ay = 0.f;
    for (int base = 0; base < d; base += 64) {
        int nrem = min(64, d - base);
        int myid = 0;
        if (base + lane < d) myid = bucket[s + base + lane];
        int j = 0;
        for (; j + 8 <= nrem; j += 8) {
            int i0 = __shfl(myid, j + 0), i1 = __shfl(myid, j + 1);
            int i2 = __shfl(myid, j + 2), i3 = __shfl(myid, j + 3);
            int i4 = __shfl(myid, j + 4), i5 = __shfl(myid, j + 5);
            int i6 = __shfl(myid, j + 6), i7 = __shfl(myid, j + 7);
            unsigned v0 = h1[(size_t)i0 * 64 + lane];
            unsigned v1 = h1[(size_t)i1 * 64 + lane];
            unsigned v2 = h1[(size_t)i2 * 64 + lane];
            unsigned v3 = h1[(size_t)i3 * 64 + lane];
            unsigned v4 = h1[(size_t)i4 * 64 + lane];
            unsigned v5 = h1[(size_t)i5 * 64 + lane];
            unsigned v6 = h1[(size_t)i6 * 64 + lane];
            unsigned v7 = h1[(size_t)i7 * 64 + lane];
            ax += ((bflo(v0) + bflo(v1)) + (bflo(v2) + bflo(v3))) +
                  ((bflo(v4) + bflo(v5)) + (bflo(v6) + bflo(v7)));
            ay += ((bfhi(v0) + bfhi(v1)) + (bfhi(v2) + bfhi(v3))) +
                  ((bfhi(v4) + bfhi(v5)) + (bfhi(v6) + bfhi(v7)));
        }
        for (; j < nrem; ++j) {
            int id = __shfl(myid, j);
            unsigned v = h1[(size_t)id * 64 + lane];
            ax += bflo(v);
            ay += bfhi(v);
        }
    }
    unsigned self = h1[(size_t)node * 64 + lane];
    float inv = 1.f / fmaxf((float)d - 1.f, 1.f);
    ax = (ax - bflo(self)) * inv;
    ay = (ay - bfhi(self)) * inv;
    __builtin_nontemporal_store(pack2(ax, ay), &((unsigned*)agg)[(size_t)node * 64 + lane]);
}

// ---------------- MFMA GEMM helpers ----------------

__device__ __forceinline__ bf16x8 ldfrag(const unsigned short* sm, int row, int ks, int lg) {
    unsigned g = (unsigned)((ks * 4 + lg) ^ (row & 7));
    return __builtin_bit_cast(bf16x8, *(const u32x4*)(sm + row * 64 + g * 8));
}
__device__ __forceinline__ void st8(unsigned short* sm, int row, int c4, unsigned lo, unsigned hi) {
    unsigned off = (unsigned)row * 64 + ((((unsigned)c4 >> 1) ^ (row & 7)) << 3) + ((c4 & 1) << 2);
    *(u32x2*)(sm + off) = (u32x2){lo, hi};
}

// ---------------- h0 = emb[i+1] + lrelu(content @ projW^T + b) : bf16 out ----------------

__global__ __launch_bounds__(256) void k_h0(const float* __restrict__ content,
                                            const float* __restrict__ projW,
                                            const float* __restrict__ projB,
                                            const float* __restrict__ emb,
                                            unsigned short* __restrict__ h) {
    __shared__ unsigned short sA[64 * 64];
    __shared__ unsigned short sB[128 * 64];
    int bm = blockIdx.x * 64;
    int tid = threadIdx.x;
    int wid = tid >> 6, l = tid & 63, lr = l & 15, lg = l >> 4;
    int wm = (wid & 1) * 32, wn = (wid >> 1) * 64;
    f32x4 acc[2][4];
    #pragma unroll
    for (int mf = 0; mf < 2; ++mf)
        #pragma unroll
        for (int nf = 0; nf < 4; ++nf) acc[mf][nf] = (f32x4){0.f, 0.f, 0.f, 0.f};

    for (int k0 = 0; k0 < 320; k0 += 64) {
        for (int idx = tid; idx < 64 * 16; idx += 256) {
            int r = idx >> 4, c4 = idx & 15;
            int gi = bm + r, k = k0 + c4 * 4;
            float4 v = make_float4(0.f, 0.f, 0.f, 0.f);
            if (gi < Nn && k < Cc) v = *(const float4*)(content + (size_t)gi * Cc + k);
            st8(sA, r, c4, pack2(v.x, v.y), pack2(v.z, v.w));
        }
        for (int idx = tid; idx < 128 * 16; idx += 256) {
            int r = idx >> 4, c4 = idx & 15;
            int k = k0 + c4 * 4;
            float4 v = make_float4(0.f, 0.f, 0.f, 0.f);
            if (k < Cc) v = *(const float4*)(projW + (size_t)r * Cc + k);
            st8(sB, r, c4, pack2(v.x, v.y), pack2(v.z, v.w));
        }
        __syncthreads();
        #pragma unroll
        for (int ks = 0; ks < 2; ++ks) {
            bf16x8 a[2], b[4];
            #pragma unroll
            for (int mf = 0; mf < 2; ++mf) a[mf] = ldfrag(sA, wm + mf * 16 + lr, ks, lg);
            #pragma unroll
            for (int nf = 0; nf < 4; ++nf) b[nf] = ldfrag(sB, wn + nf * 16 + lr, ks, lg);
            #pragma unroll
            for (int mf = 0; mf < 2; ++mf)
                #pragma unroll
                for (int nf = 0; nf < 4; ++nf)
                    acc[mf][nf] = __builtin_amdgcn_mfma_f32_16x16x32_bf16(a[mf], b[nf], acc[mf][nf], 0, 0, 0);
        }
        __syncthreads();
    }

    float pb[4];
    #pragma unroll
    for (int nf = 0; nf < 4; ++nf) pb[nf] = projB[wn + nf * 16 + lr];
    #pragma unroll
    for (int mf = 0; mf < 2; ++mf)
        #pragma unroll
        for (int v = 0; v < 4; ++v) {
            int row = bm + wm + mf * 16 + lg * 4 + v;
            if (row >= Nn) continue;
            #pragma unroll
            for (int nf = 0; nf < 4; ++nf) {
                int col = wn + nf * 16 + lr;
                float x = lrelu(acc[mf][nf][v] + pb[nf]) + emb[(size_t)(row + 1) * Dd + col];
                h[(size_t)row * Dd + col] = (unsigned short)f2bf(x);
            }
        }
}

// ---------------- SAGE layer: rownorm(act(concat(h,agg) @ W^T + b)) ----------------

template <int MODE>
__global__ __launch_bounds__(256) void k_layer(const unsigned short* __restrict__ hsrc,
                                               const unsigned short* __restrict__ asrc,
                                               const float* __restrict__ W,
                                               const float* __restrict__ bias,
                                               void* __restrict__ outp) {
    __shared__ unsigned short sA[64 * 64];
    __shared__ unsigned short sB[128 * 64];
    __shared__ float rowsum[64];
    int bm = blockIdx.x * 64;
    int tid = threadIdx.x;
    int wid = tid >> 6, l = tid & 63, lr = l & 15, lg = l >> 4;
    int wm = (wid & 1) * 32, wn = (wid >> 1) * 64;
    if (tid < 64) rowsum[tid] = 0.f;
    f32x4 acc[2][4];
    #pragma unroll
    for (int mf = 0; mf < 2; ++mf)
        #pragma unroll
        for (int nf = 0; nf < 4; ++nf) acc[mf][nf] = (f32x4){0.f, 0.f, 0.f, 0.f};

    for (int kc = 0; kc < 4; ++kc) {
        const unsigned short* Asrc = (kc < 2) ? hsrc : asrc;
        int koff = (kc & 1) * 64;
        for (int idx = tid; idx < 64 * 8; idx += 256) {
            int r = idx >> 3, g = idx & 7;
            int gi = bm + r;
            u32x4 v = (u32x4){0u, 0u, 0u, 0u};
            if (gi < Nn) v = *(const u32x4*)(Asrc + (size_t)gi * Dd + koff + g * 8);
            unsigned gg = (unsigned)g ^ (r & 7);
            *(u32x4*)(sA + r * 64 + gg * 8) = v;
        }
        for (int idx = tid; idx < 128 * 16; idx += 256) {
            int r = idx >> 4, c4 = idx & 15;
            int k = kc * 64 + c4 * 4;
            float4 v = *(const float4*)(W + (size_t)r * 256 + k);
            st8(sB, r, c4, pack2(v.x, v.y), pack2(v.z, v.w));
        }
        __syncthreads();
        #pragma unroll
        for (int ks = 0; ks < 2; ++ks) {
            bf16x8 a[2], b[4];
            #pragma unroll
            for (int mf = 0; mf < 2; ++mf) a[mf] = ldfrag(sA, wm + mf * 16 + lr, ks, lg);
            #pragma unroll
            for (int nf = 0; nf < 4; ++nf) b[nf] = ldfrag(sB, wn + nf * 16 + lr, ks, lg);
            #pragma unroll
            for (int mf = 0; mf < 2; ++mf)
                #pragma unroll
                for (int nf = 0; nf < 4; ++nf)
                    acc[mf][nf] = __builtin_amdgcn_mfma_f32_16x16x32_bf16(a[mf], b[nf], acc[mf][nf], 0, 0, 0);
        }
        __syncthreads();
    }

    float pb[4];
    #pragma unroll
    for (int nf = 0; nf < 4; ++nf) pb[nf] = bias[wn + nf * 16 + lr];
    float ps[2][4];
    #pragma unroll
    for (int mf = 0; mf < 2; ++mf)
        #pragma unroll
        for (int v = 0; v < 4; ++v) {
            float s = 0.f;
            #pragma unroll
            for (int nf = 0; nf < 4; ++nf) {
                float x = acc[mf][nf][v] + pb[nf];
                if (MODE == 0) x = lrelu(x);
                acc[mf][nf][v] = x;
                s += x * x;
            }
            ps[mf][v] = s;
        }
    #pragma unroll
    for (int off = 1; off < 16; off <<= 1)
        #pragma unroll
        for (int mf = 0; mf < 2; ++mf)
            #pragma unroll
            for (int v = 0; v < 4; ++v) ps[mf][v] += __shfl_xor(ps[mf][v], off, 16);
    if (lr == 0) {
        #pragma unroll
        for (int mf = 0; mf < 2; ++mf)
            #pragma unroll
            for (int v = 0; v < 4; ++v)
                atomicAdd(&rowsum[wm + mf * 16 + lg * 4 + v], ps[mf][v]);
    }
    __syncthreads();
    #pragma unroll
    for (int mf = 0; mf < 2; ++mf)
        #pragma unroll
        for (int v = 0; v < 4; ++v) {
            int row = bm + wm + mf * 16 + lg * 4 + v;
            if (row >= Nn) continue;
            float inv = 1.f / fmaxf(sqrtf(rowsum[wm + mf * 16 + lg * 4 + v]), 1e-6f);
            #pragma unroll
            for (int nf = 0; nf < 4; ++nf) {
                int col = wn + nf * 16 + lr;
                float x = acc[mf][nf][v] * inv;
                if (MODE == 0)
                    ((unsigned short*)outp)[(size_t)row * Dd + col] = (unsigned short)f2bf(x);
                else
                    ((float*)outp)[(size_t)row * Dd + col] = x;
            }
        }
}

// ---------------- launch ----------------

extern "C" void kernel_launch(void* const* d_in, const int* in_sizes, int n_in,
                              void* d_out, int out_size, void* d_ws, size_t ws_size,
                              hipStream_t stream) {
    const float* node_emb = (const float*)d_in[0];
    const float* content  = (const float*)d_in[1];
    const float* projW    = (const float*)d_in[2];
    const float* projB    = (const float*)d_in[3];
    const float* W1 = (const float*)d_in[4];
    const float* b1 = (const float*)d_in[5];
    const float* W2 = (const float*)d_in[6];
    const float* b2 = (const float*)d_in[7];
    const int* esrc = (const int*)d_in[8];
    const int* edst = (const int*)d_in[9];
    const int ET = in_sizes[8];
    float* out = (float*)d_out;

    // workspace layout (~55 MB)
    unsigned short* h0  = (unsigned short*)d_ws;          // N*128 bf16
    unsigned short* h1  = h0 + (size_t)Nn * Dd;           // N*128 bf16
    unsigned short* agg = h1 + (size_t)Nn * Dd;           // N*128 bf16
    int* offs      = (int*)(agg + (size_t)Nn * Dd);       // N
    int* deg       = offs + Nn;                           // N
    int* binCursor = deg + Nn;                            // NBINS
    int* bucket    = binCursor + NBINS;                   // NBINS*CAP
    unsigned* pairs = (unsigned*)(bucket + (size_t)NBINS * CAP);  // NBINS*CAP

    hipMemsetAsync(binCursor, 0, NBINS * sizeof(int), stream);
    k_binscatter<<<(ET + SCHUNK - 1) / SCHUNK, 512, 0, stream>>>(esrc, edst, binCursor, pairs, ET);
    k_binsort<<<NBINS, 256, 0, stream>>>(pairs, binCursor, offs, deg, bucket);

    k_h0<<<(Nn + 63) / 64, 256, 0, stream>>>(content, projW, projB, node_emb, h0);

    k_agg<<<(Nn + 3) / 4, 256, 0, stream>>>(h0, offs, deg, bucket, agg);
    k_layer<0><<<(Nn + 63) / 64, 256, 0, stream>>>(h0, agg, W1, b1, (void*)h1);

    k_agg<<<(Nn + 3) / 4, 256, 0, stream>>>(h1, offs, deg, bucket, agg);
    k_layer<1><<<(Nn + 63) / 64, 256, 0, stream>>>(h1, agg, W2, b2, (void*)out);
}